// Round 7
// baseline (139.853 us; speedup 1.0000x reference)
//
#include <hip/hip_runtime.h>
#include <cstdint>

#define B_ 32
#define C_ 2048
#define Q_ 128
#define D_ 128
#define CT 64
#define NEG_INF_F (-1.0e9f)

typedef __attribute__((ext_vector_type(8))) short bf16x8;
typedef __attribute__((ext_vector_type(4))) float f32x4;

__device__ inline void split_f32(float v, short& h, short& l) {
    unsigned u  = __float_as_uint(v);
    unsigned hb = u & 0xffff0000u;          // truncated bf16 (hi)
    float lo = v - __uint_as_float(hb);     // exact residual
    h = (short)(hb >> 16);
    l = (short)(__float_as_uint(lo) >> 16);
}

// ---------- prep: qw2e (q.w2 + mask), bf16-split of (qry*w3) and qry^T ----------
__global__ __launch_bounds__(256)
void cqa_prep(const float* __restrict__ qry, const float* __restrict__ w,
              const int* __restrict__ qmask, float* __restrict__ qw2e_g,
              unsigned short* __restrict__ qw3Hi, unsigned short* __restrict__ qw3Lo,
              unsigned short* __restrict__ qTHi, unsigned short* __restrict__ qTLo)
{
    const int b = blockIdx.y, ch = blockIdx.x;   // ch: 16-row chunk of q
    const int t = threadIdx.x;
    const float* qb = qry + (size_t)b * Q_ * D_;

    if (t < 32) {
        int rl = t >> 1, part = t & 1;
        int q = ch * 16 + rl;
        const float* p  = qb + q * D_ + part * 64;
        const float* wp = w + D_ + part * 64;
        float s = 0.f;
        #pragma unroll
        for (int j = 0; j < 64; j += 4) {
            float4 a4 = *(const float4*)(p + j);
            float4 w4 = *(const float4*)(wp + j);
            s += a4.x*w4.x + a4.y*w4.y + a4.z*w4.z + a4.w*w4.w;
        }
        s += __shfl_xor(s, 1, 2);
        if (!part) {
            float madd = (1.0f - (float)qmask[b * Q_ + q]) * NEG_INF_F;
            qw2e_g[b * Q_ + q] = s + madd;
        }
    }
    #pragma unroll
    for (int i = 0; i < 8; ++i) {
        int idx = t + i * 256;            // 0..2047 over 16 rows x 128 d
        int ql = idx >> 7, d = idx & 127;
        int q = ch * 16 + ql;
        float v  = qb[q * D_ + d];
        float vw = v * w[2 * D_ + d];
        short h, l;
        split_f32(vw, h, l);
        qw3Hi[((size_t)b * Q_ + q) * D_ + d] = (unsigned short)h;
        qw3Lo[((size_t)b * Q_ + q) * D_ + d] = (unsigned short)l;
        split_f32(v, h, l);
        qTHi[((size_t)b * D_ + d) * Q_ + q] = (unsigned short)h;
        qTLo[((size_t)b * D_ + d) * Q_ + q] = (unsigned short)l;
    }
}

// ---------- main: MFMA GEMMs with direct-global fragments; LDS only for P/Tr ----
__global__ __launch_bounds__(256, 4)
void cqa_main(const float* __restrict__ ctx, const float* __restrict__ w,
              const float* __restrict__ qw2e_g,
              const unsigned short* __restrict__ qw3Hi, const unsigned short* __restrict__ qw3Lo,
              const unsigned short* __restrict__ qTHi, const unsigned short* __restrict__ qTLo,
              float* __restrict__ out, float* __restrict__ m_out)
{
    __shared__ __align__(16) char smem[34816];
    short* PHi  = (short*)smem;                 // [64][136] bf16, GEMM2 A-operand
    float* Tr   = (float*)smem;                 // [64][132] f32, epilogue (overlays PHi)
    float* cw1  = (float*)(smem + 33792);       // 64 f32
    float* qw2e = (float*)(smem + 34048);       // 128 f32

    const int b   = blockIdx.y;
    const int c0  = blockIdx.x * CT;
    const int tid = threadIdx.x;
    const int lane = tid & 63;
    const int wv   = tid >> 6;
    const int w16  = wv * 16;
    const int lm   = lane & 15;
    const int lg   = lane >> 4;    // 0..3
    const int lk   = lg * 8;       // k-slot start within 32-chunk

    const float* ctxb = ctx + ((size_t)b * C_ + c0) * D_;

    // cw1[c] = ctx_row . w1 (4 threads/row, coalesced float4)
    {
        int row = tid >> 2, part = tid & 3;
        const float* p  = ctxb + row * D_ + part * 32;
        const float* wp = w + part * 32;
        float s = 0.f;
        #pragma unroll
        for (int j = 0; j < 32; j += 4) {
            float4 c4 = *(const float4*)(p + j);
            float4 w4 = *(const float4*)(wp + j);
            s += c4.x*w4.x + c4.y*w4.y + c4.z*w4.z + c4.w*w4.w;
        }
        s += __shfl_xor(s, 1, 4);
        s += __shfl_xor(s, 2, 4);
        if (!part) cw1[row] = s;
    }
    if (tid < Q_) qw2e[tid] = qw2e_g[b * Q_ + tid];
    __syncthreads();

    float qe[8];
    #pragma unroll
    for (int f = 0; f < 8; ++f) qe[f] = qw2e[f * 16 + lm];
    float cwr[4];
    #pragma unroll
    for (int r = 0; r < 4; ++r) cwr[r] = cw1[w16 + lg * 4 + r];

    const f32x4 vzero = {0.f, 0.f, 0.f, 0.f};
    f32x4 acc[8];
    #pragma unroll
    for (int f = 0; f < 8; ++f) acc[f] = vzero;

    const unsigned short* qw3Hb = qw3Hi + (size_t)b * Q_ * D_;
    const unsigned short* qw3Lb = qw3Lo + (size_t)b * Q_ * D_;
    const float* arow = ctxb + (size_t)(w16 + lm) * D_;

    // ---- GEMM1: S[c][q], wave = 16 c-rows x 128 q-cols, no LDS, no barriers
    #pragma unroll
    for (int k0 = 0; k0 < D_; k0 += 32) {
        float4 v0 = *(const float4*)(arow + k0 + lk);
        float4 v1 = *(const float4*)(arow + k0 + lk + 4);
        float vv[8] = {v0.x, v0.y, v0.z, v0.w, v1.x, v1.y, v1.z, v1.w};
        bf16x8 aH, aL;
        #pragma unroll
        for (int i = 0; i < 8; ++i) { short hh, ll; split_f32(vv[i], hh, ll); aH[i]=hh; aL[i]=ll; }
        #pragma unroll
        for (int f = 0; f < 8; ++f) {
            size_t off = (size_t)(f * 16 + lm) * D_ + k0 + lk;
            bf16x8 bH = *(const bf16x8*)(qw3Hb + off);
            bf16x8 bL = *(const bf16x8*)(qw3Lb + off);
            acc[f] = __builtin_amdgcn_mfma_f32_16x16x32_bf16(aH, bH, acc[f], 0, 0, 0);
            acc[f] = __builtin_amdgcn_mfma_f32_16x16x32_bf16(aH, bL, acc[f], 0, 0, 0);
            acc[f] = __builtin_amdgcn_mfma_f32_16x16x32_bf16(aL, bH, acc[f], 0, 0, 0);
        }
    }

    // ---- softmax over q; P -> LDS bf16 (hi only); row max (+cw) -> m_out
    float inv[4];
    #pragma unroll
    for (int r = 0; r < 4; ++r) {
        float sv[8];
        float mx = -3.0e38f;
        #pragma unroll
        for (int f = 0; f < 8; ++f) {
            sv[f] = acc[f][r] + qe[f];
            mx = fmaxf(mx, sv[f]);
        }
        mx = fmaxf(mx, __shfl_xor(mx, 1, 16));
        mx = fmaxf(mx, __shfl_xor(mx, 2, 16));
        mx = fmaxf(mx, __shfl_xor(mx, 4, 16));
        mx = fmaxf(mx, __shfl_xor(mx, 8, 16));
        int lrow = w16 + lg * 4 + r;
        float s = 0.f;
        #pragma unroll
        for (int f = 0; f < 8; ++f) {
            float p = __expf(sv[f] - mx);
            s += p;
            PHi[lrow * 136 + f * 16 + lm] = (short)(__float_as_uint(p) >> 16);
        }
        s += __shfl_xor(s, 1, 16);
        s += __shfl_xor(s, 2, 16);
        s += __shfl_xor(s, 4, 16);
        s += __shfl_xor(s, 8, 16);
        inv[r] = 1.0f / s;
        if (lm == 0) m_out[(size_t)b * C_ + c0 + lrow] = mx + cwr[r];
    }
    __syncthreads();   // P visible (and safely ordered vs later Tr overlay)

    // ---- GEMM2: c2q[c][d] = sum_q P[c][q]*qry[q][d]; A=P(LDS), B=qT(global)
    f32x4 acc2[8];
    #pragma unroll
    for (int f = 0; f < 8; ++f) acc2[f] = vzero;

    const unsigned short* qTHb = qTHi + (size_t)b * Q_ * D_;
    const unsigned short* qTLb = qTLo + (size_t)b * Q_ * D_;

    #pragma unroll
    for (int q0 = 0; q0 < Q_; q0 += 32) {
        bf16x8 aH = *(const bf16x8*)(PHi + (w16 + lm) * 136 + q0 + lk);
        #pragma unroll
        for (int f = 0; f < 8; ++f) {
            size_t off = (size_t)(f * 16 + lm) * Q_ + q0 + lk;
            bf16x8 bH = *(const bf16x8*)(qTHb + off);
            bf16x8 bL = *(const bf16x8*)(qTLb + off);
            acc2[f] = __builtin_amdgcn_mfma_f32_16x16x32_bf16(aH, bH, acc2[f], 0, 0, 0);
            acc2[f] = __builtin_amdgcn_mfma_f32_16x16x32_bf16(aH, bL, acc2[f], 0, 0, 0);
        }
    }
    __syncthreads();   // all GEMM2 LDS reads done before Tr overwrites PHi

    // ---- transpose c2q through LDS, then coalesced stores of out[0:3D)
    #pragma unroll
    for (int r = 0; r < 4; ++r) {
        int lrow = w16 + lg * 4 + r;
        #pragma unroll
        for (int f = 0; f < 8; ++f)
            Tr[lrow * 132 + f * 16 + lm] = acc2[f][r] * inv[r];
    }
    __syncthreads();
    {
        int rsel = tid >> 5;
        int d    = (tid & 31) * 4;
        #pragma unroll
        for (int pass = 0; pass < 8; ++pass) {
            int row = pass * 8 + rsel;
            float4 a  = *(const float4*)(Tr + row * 132 + d);
            float4 cv = *(const float4*)(ctxb + (size_t)row * D_ + d);
            size_t obase = ((size_t)b * C_ + c0 + row) * (4 * D_);
            float4 p;
            p.x = cv.x*a.x; p.y = cv.y*a.y; p.z = cv.z*a.z; p.w = cv.w*a.w;
            *(float4*)(out + obase + d)          = cv;
            *(float4*)(out + obase + D_ + d)     = a;
            *(float4*)(out + obase + 2 * D_ + d) = p;
        }
    }
}

// ---------------- per-batch max / sumexp of m ----------------
__global__ __launch_bounds__(256)
void cqa_bstats(const float* __restrict__ m, float* __restrict__ bstats)
{
    int b = blockIdx.x;
    const float* mb = m + (size_t)b * C_;
    int tid = threadIdx.x;
    float vals[8];
    float mx = -3.0e38f;
    #pragma unroll
    for (int i = 0; i < 8; ++i) {
        vals[i] = mb[tid + i*256];
        mx = fmaxf(mx, vals[i]);
    }
    #pragma unroll
    for (int o = 1; o < 64; o <<= 1) mx = fmaxf(mx, __shfl_xor(mx, o, 64));
    __shared__ float red[4], red2[4];
    int wv = tid >> 6, ln = tid & 63;
    if (ln == 0) red[wv] = mx;
    __syncthreads();
    mx = fmaxf(fmaxf(red[0], red[1]), fmaxf(red[2], red[3]));
    float s = 0.f;
    #pragma unroll
    for (int i = 0; i < 8; ++i) s += __expf(vals[i] - mx);
    #pragma unroll
    for (int o = 1; o < 64; o <<= 1) s += __shfl_xor(s, o, 64);
    if (ln == 0) red2[wv] = s;
    __syncthreads();
    if (tid == 0) {
        bstats[b*2]   = mx;
        bstats[b*2+1] = red2[0] + red2[1] + red2[2] + red2[3];
    }
}

// ---------------- q2c partials (deterministic, no atomics) ----------------
__global__ __launch_bounds__(256)
void cqa_q2c_part(const float* __restrict__ ctx, const float* __restrict__ m,
                  const float* __restrict__ bstats, float* __restrict__ part)
{
    int b = blockIdx.y, ch = blockIdx.x;
    int tid = threadIdx.x;
    int d = tid & 127, half = tid >> 7;
    float bmax = bstats[b*2];
    float inv  = 1.0f / bstats[b*2+1];
    const float* mb = m + (size_t)b*C_ + ch*256;
    const float* cb = ctx + ((size_t)b*C_ + ch*256) * D_;
    float acc = 0.f;
    for (int i = half; i < 256; i += 2) {
        float wgt = __expf(mb[i] - bmax);
        acc += wgt * cb[(size_t)i * D_ + d];
    }
    __shared__ float sh[128];
    if (half) sh[d] = acc;
    __syncthreads();
    if (!half) part[((size_t)b*8 + ch) * D_ + d] = (acc + sh[d]) * inv;
}

__global__ __launch_bounds__(256)
void cqa_q2c_sum(const float* __restrict__ part, float* __restrict__ q2c)
{
    int i = blockIdx.x * 256 + threadIdx.x;
    if (i >= B_ * D_) return;
    int b = i >> 7, d = i & 127;
    float s = 0.f;
    #pragma unroll
    for (int ch = 0; ch < 8; ++ch) s += part[((size_t)b*8 + ch)*D_ + d];
    q2c[i] = s;
}

// ---------------- out[:,:,384:512) = ctx * q2c (broadcast) ----------------
__global__ __launch_bounds__(256)
void cqa_out4(const float* __restrict__ ctx, const float* __restrict__ q2c,
              float* __restrict__ out)
{
    size_t i = (size_t)blockIdx.x * 256 + threadIdx.x;
    const size_t n4 = (size_t)B_*C_*D_/4;
    if (i >= n4) return;
    size_t bc = i >> 5;
    int d4 = (int)(i & 31);
    int b  = (int)(bc >> 11);
    float4 c4 = reinterpret_cast<const float4*>(ctx)[i];
    float4 g4 = reinterpret_cast<const float4*>(q2c)[b*32 + d4];
    float4 o;
    o.x = c4.x*g4.x; o.y = c4.y*g4.y; o.z = c4.z*g4.z; o.w = c4.w*g4.w;
    reinterpret_cast<float4*>(out)[bc*128 + 96 + d4] = o;
}

extern "C" void kernel_launch(void* const* d_in, const int* in_sizes, int n_in,
                              void* d_out, int out_size, void* d_ws, size_t ws_size,
                              hipStream_t stream)
{
    const float* ctx   = (const float*)d_in[0];
    const float* qry   = (const float*)d_in[1];
    const float* w     = (const float*)d_in[2];
    const int*   qmask = (const int*)d_in[3];
    float* out = (float*)d_out;
    float* ws  = (float*)d_ws;

    float* m_ws    = ws;                        // 65536 f32
    float* bstats  = ws + 65536;                // 64 (pad 128)
    float* part    = ws + 65664;                // 32768
    float* q2c     = ws + 98432;                // 4096
    float* qw2e_g  = ws + 102528;               // 4096
    unsigned short* bf = (unsigned short*)(ws + 106624);
    unsigned short* qw3Hi = bf;                 // 524288 each
    unsigned short* qw3Lo = bf + 524288;
    unsigned short* qTHi  = bf + 2*524288;
    unsigned short* qTLo  = bf + 3*524288;

    cqa_prep<<<dim3(8, B_), 256, 0, stream>>>(qry, w, qmask, qw2e_g,
                                              qw3Hi, qw3Lo, qTHi, qTLo);
    cqa_main<<<dim3(C_/CT, B_), 256, 0, stream>>>(ctx, w, qw2e_g,
                                                  qw3Hi, qw3Lo, qTHi, qTLo,
                                                  out, m_ws);
    cqa_bstats<<<B_, 256, 0, stream>>>(m_ws, bstats);
    cqa_q2c_part<<<dim3(8, B_), 256, 0, stream>>>(ctx, m_ws, bstats, part);
    cqa_q2c_sum<<<(B_*D_ + 255)/256, 256, 0, stream>>>(part, q2c);
    cqa_out4<<<(int)(((size_t)B_*C_*D_/4 + 255)/256), 256, 0, stream>>>(ctx, q2c, out);
}

// Round 8
// 100.898 us; speedup vs baseline: 1.3861x; 1.3861x over previous
//
#include <hip/hip_runtime.h>
#include <cstdint>

#define B_ 32
#define C_ 2048
#define Q_ 128
#define D_ 128
#define CT 64
#define NEG_INF_F (-1.0e9f)

typedef __attribute__((ext_vector_type(8))) short bf16x8;
typedef __attribute__((ext_vector_type(4))) float f32x4;

__device__ inline void split_f32(float v, short& h, short& l) {
    unsigned u  = __float_as_uint(v);
    unsigned hb = u & 0xffff0000u;          // truncated bf16 (hi)
    float lo = v - __uint_as_float(hb);     // exact residual
    h = (short)(hb >> 16);
    l = (short)(__float_as_uint(lo) >> 16);
}

// ---------- prep: qw2e (q.w2 + mask), bf16-split of (qry*w3) and qry^T ----------
__global__ __launch_bounds__(256)
void cqa_prep(const float* __restrict__ qry, const float* __restrict__ w,
              const int* __restrict__ qmask, float* __restrict__ qw2e_g,
              unsigned short* __restrict__ qw3Hi, unsigned short* __restrict__ qw3Lo,
              unsigned short* __restrict__ qTHi, unsigned short* __restrict__ qTLo)
{
    const int b = blockIdx.y, ch = blockIdx.x;   // ch: 16-row chunk of q
    const int t = threadIdx.x;
    const float* qb = qry + (size_t)b * Q_ * D_;

    if (t < 32) {
        int rl = t >> 1, part = t & 1;
        int q = ch * 16 + rl;
        const float* p  = qb + q * D_ + part * 64;
        const float* wp = w + D_ + part * 64;
        float s = 0.f;
        #pragma unroll
        for (int j = 0; j < 64; j += 4) {
            float4 a4 = *(const float4*)(p + j);
            float4 w4 = *(const float4*)(wp + j);
            s += a4.x*w4.x + a4.y*w4.y + a4.z*w4.z + a4.w*w4.w;
        }
        s += __shfl_xor(s, 1, 2);
        if (!part) {
            float madd = (1.0f - (float)qmask[b * Q_ + q]) * NEG_INF_F;
            qw2e_g[b * Q_ + q] = s + madd;
        }
    }
    #pragma unroll
    for (int i = 0; i < 8; ++i) {
        int idx = t + i * 256;            // 0..2047 over 16 rows x 128 d
        int ql = idx >> 7, d = idx & 127;
        int q = ch * 16 + ql;
        float v  = qb[q * D_ + d];
        float vw = v * w[2 * D_ + d];
        short h, l;
        split_f32(vw, h, l);
        qw3Hi[((size_t)b * Q_ + q) * D_ + d] = (unsigned short)h;
        qw3Lo[((size_t)b * Q_ + q) * D_ + d] = (unsigned short)l;
        split_f32(v, h, l);
        qTHi[((size_t)b * D_ + d) * Q_ + q] = (unsigned short)h;
        qTLo[((size_t)b * D_ + d) * Q_ + q] = (unsigned short)l;
    }
}

// stage cols [col0,col0+32) of a [128][128]-short row-major matrix into a
// 16KB LDS buffer (Hi [128][32] @ +0, Lo @ +4096 shorts) via async DMA.
// global_load_lds: LDS dest = wave-uniform base + lane*16B (linear), so the
// per-lane GLOBAL address must match that linear order (guide m104/m173).
__device__ __forceinline__ void stage_b(const unsigned short* __restrict__ gH,
                                        const unsigned short* __restrict__ gL,
                                        int col0, short* sb, int wv, int lane)
{
    #pragma unroll
    for (int j = 0; j < 2; ++j) {
        int seg = wv * 2 + j;                 // 1KB segment 0..7
        int li  = seg * 64 + lane;            // 16B-unit linear index
        int row = li >> 2;
        int col = (li & 3) * 8;
        const unsigned short* sH = gH + (size_t)row * 128 + col0 + col;
        const unsigned short* sL = gL + (size_t)row * 128 + col0 + col;
        __builtin_amdgcn_global_load_lds(
            (const __attribute__((address_space(1))) void*)sH,
            (__attribute__((address_space(3))) void*)(sb + seg * 512), 16, 0, 0);
        __builtin_amdgcn_global_load_lds(
            (const __attribute__((address_space(1))) void*)sL,
            (__attribute__((address_space(3))) void*)(sb + 4096 + seg * 512), 16, 0, 0);
    }
}

// ---------- main: MFMA GEMMs, async-DMA double-buffered B staging ----------
__global__ __launch_bounds__(256, 3)
void cqa_main(const float* __restrict__ ctx, const float* __restrict__ w,
              const float* __restrict__ qw2e_g,
              const unsigned short* __restrict__ qw3Hi, const unsigned short* __restrict__ qw3Lo,
              const unsigned short* __restrict__ qTHi, const unsigned short* __restrict__ qTLo,
              float* __restrict__ out, float* __restrict__ m_out)
{
    __shared__ __align__(16) char smem[50944];
    short* SB   = (short*)smem;                 // 2 x 16KB stage buffers (Hi/Lo)
    short* PHi  = (short*)(smem + 32768);       // [64][136] bf16
    float* Tr   = (float*)smem;                 // [64][132] f32, epilogue overlay
    float* cw1  = (float*)(smem + 50176);       // 64 f32
    float* qw2e = (float*)(smem + 50432);       // 128 f32

    const int b   = blockIdx.y;
    const int c0  = blockIdx.x * CT;
    const int tid = threadIdx.x;
    const int lane = tid & 63;
    const int wv   = tid >> 6;
    const int w16  = wv * 16;
    const int lm   = lane & 15;
    const int lg   = lane >> 4;    // 0..3
    const int lk   = lg * 8;       // k-slot start within 32-chunk

    const float* ctxb = ctx + ((size_t)b * C_ + c0) * D_;
    const unsigned short* qw3Hb = qw3Hi + (size_t)b * Q_ * D_;
    const unsigned short* qw3Lb = qw3Lo + (size_t)b * Q_ * D_;
    const unsigned short* qTHb  = qTHi + (size_t)b * Q_ * D_;
    const unsigned short* qTLb  = qTLo + (size_t)b * Q_ * D_;

    // kick off DMA of GEMM1 chunk 0 immediately
    stage_b(qw3Hb, qw3Lb, 0, SB, wv, lane);

    // cw1[c] = ctx_row . w1 (4 threads/row, coalesced float4)
    {
        int row = tid >> 2, part = tid & 3;
        const float* p  = ctxb + row * D_ + part * 32;
        const float* wp = w + part * 32;
        float s = 0.f;
        #pragma unroll
        for (int j = 0; j < 32; j += 4) {
            float4 c4 = *(const float4*)(p + j);
            float4 w4 = *(const float4*)(wp + j);
            s += c4.x*w4.x + c4.y*w4.y + c4.z*w4.z + c4.w*w4.w;
        }
        s += __shfl_xor(s, 1, 4);
        s += __shfl_xor(s, 2, 4);
        if (!part) cw1[row] = s;
    }
    if (tid < Q_) qw2e[tid] = qw2e_g[b * Q_ + tid];

    // preload ALL A-fragments (ctx rows) for the 4 k-chunks; overlaps DMA
    const float* arow = ctxb + (size_t)(w16 + lm) * D_;
    bf16x8 aHr[4], aLr[4];
    #pragma unroll
    for (int t = 0; t < 4; ++t) {
        float4 v0 = *(const float4*)(arow + t * 32 + lk);
        float4 v1 = *(const float4*)(arow + t * 32 + lk + 4);
        float vv[8] = {v0.x, v0.y, v0.z, v0.w, v1.x, v1.y, v1.z, v1.w};
        #pragma unroll
        for (int i = 0; i < 8; ++i) {
            short hh, ll; split_f32(vv[i], hh, ll);
            aHr[t][i] = hh; aLr[t][i] = ll;
        }
    }
    __syncthreads();   // S0: stage(G1,0) complete, cw1/qw2e visible

    float qe[8];
    #pragma unroll
    for (int f = 0; f < 8; ++f) qe[f] = qw2e[f * 16 + lm];
    float cwr[4];
    #pragma unroll
    for (int r = 0; r < 4; ++r) cwr[r] = cw1[w16 + lg * 4 + r];

    const f32x4 vzero = {0.f, 0.f, 0.f, 0.f};
    f32x4 acc[8];
    #pragma unroll
    for (int f = 0; f < 8; ++f) acc[f] = vzero;

    // ---- GEMM1: S[c][q]; B from LDS (double-buffered DMA), A from regs
    #pragma unroll
    for (int t = 0; t < 4; ++t) {
        if (t < 3) stage_b(qw3Hb, qw3Lb, (t + 1) * 32, SB + ((t + 1) & 1) * 8192, wv, lane);
        else       stage_b(qTHb,  qTLb,  0,            SB,                        wv, lane);
        const short* sb = SB + (t & 1) * 8192;
        bf16x8 aH = aHr[t], aL = aLr[t];
        #pragma unroll
        for (int f = 0; f < 8; ++f) {
            bf16x8 bH = *(const bf16x8*)(sb + (f * 16 + lm) * 32 + lk);
            bf16x8 bL = *(const bf16x8*)(sb + 4096 + (f * 16 + lm) * 32 + lk);
            acc[f] = __builtin_amdgcn_mfma_f32_16x16x32_bf16(aH, bH, acc[f], 0, 0, 0);
            acc[f] = __builtin_amdgcn_mfma_f32_16x16x32_bf16(aH, bL, acc[f], 0, 0, 0);
            acc[f] = __builtin_amdgcn_mfma_f32_16x16x32_bf16(aL, bH, acc[f], 0, 0, 0);
        }
        __syncthreads();   // drains stage issued above; guards dbuf reuse
    }

    // ---- softmax over q; P -> LDS bf16 (wave-private rows); m (+cw) -> m_out
    float inv[4];
    #pragma unroll
    for (int r = 0; r < 4; ++r) {
        float sv[8];
        float mx = -3.0e38f;
        #pragma unroll
        for (int f = 0; f < 8; ++f) {
            sv[f] = acc[f][r] + qe[f];
            mx = fmaxf(mx, sv[f]);
        }
        mx = fmaxf(mx, __shfl_xor(mx, 1, 16));
        mx = fmaxf(mx, __shfl_xor(mx, 2, 16));
        mx = fmaxf(mx, __shfl_xor(mx, 4, 16));
        mx = fmaxf(mx, __shfl_xor(mx, 8, 16));
        int lrow = w16 + lg * 4 + r;
        float s = 0.f;
        #pragma unroll
        for (int f = 0; f < 8; ++f) {
            float p = __expf(sv[f] - mx);
            s += p;
            PHi[lrow * 136 + f * 16 + lm] = (short)(__float_as_uint(p) >> 16);
        }
        s += __shfl_xor(s, 1, 16);
        s += __shfl_xor(s, 2, 16);
        s += __shfl_xor(s, 4, 16);
        s += __shfl_xor(s, 8, 16);
        inv[r] = 1.0f / s;
        if (lm == 0) m_out[(size_t)b * C_ + c0 + lrow] = mx + cwr[r];
    }
    // No barrier: P rows are wave-private (rows w16..w16+15 written & read by wave wv)

    // ---- GEMM2: c2q[c][d] = sum_q P[c][q]*qry[q][d]; A=P(LDS), B=qT(staged)
    f32x4 acc2[8];
    #pragma unroll
    for (int f = 0; f < 8; ++f) acc2[f] = vzero;

    #pragma unroll
    for (int t = 0; t < 4; ++t) {
        if (t < 3) stage_b(qTHb, qTLb, (t + 1) * 32, SB + ((t + 1) & 1) * 8192, wv, lane);
        const short* sb = SB + (t & 1) * 8192;
        bf16x8 aH = *(const bf16x8*)(PHi + (w16 + lm) * 136 + t * 32 + lk);
        #pragma unroll
        for (int f = 0; f < 8; ++f) {
            bf16x8 bH = *(const bf16x8*)(sb + (f * 16 + lm) * 32 + lk);
            bf16x8 bL = *(const bf16x8*)(sb + 4096 + (f * 16 + lm) * 32 + lk);
            acc2[f] = __builtin_amdgcn_mfma_f32_16x16x32_bf16(aH, bH, acc2[f], 0, 0, 0);
            acc2[f] = __builtin_amdgcn_mfma_f32_16x16x32_bf16(aH, bL, acc2[f], 0, 0, 0);
        }
        __syncthreads();
    }

    // ---- transpose c2q through LDS (overlay), then coalesced stores of out[0:3D)
    #pragma unroll
    for (int r = 0; r < 4; ++r) {
        int lrow = w16 + lg * 4 + r;
        #pragma unroll
        for (int f = 0; f < 8; ++f)
            Tr[lrow * 132 + f * 16 + lm] = acc2[f][r] * inv[r];
    }
    __syncthreads();
    {
        int rsel = tid >> 5;
        int d    = (tid & 31) * 4;
        #pragma unroll
        for (int pass = 0; pass < 8; ++pass) {
            int row = pass * 8 + rsel;
            float4 a  = *(const float4*)(Tr + row * 132 + d);
            float4 cv = *(const float4*)(ctxb + (size_t)row * D_ + d);
            size_t obase = ((size_t)b * C_ + c0 + row) * (4 * D_);
            float4 p;
            p.x = cv.x*a.x; p.y = cv.y*a.y; p.z = cv.z*a.z; p.w = cv.w*a.w;
            *(float4*)(out + obase + d)          = cv;
            *(float4*)(out + obase + D_ + d)     = a;
            *(float4*)(out + obase + 2 * D_ + d) = p;
        }
    }
}

// ---------------- per-batch max / sumexp of m ----------------
__global__ __launch_bounds__(256)
void cqa_bstats(const float* __restrict__ m, float* __restrict__ bstats)
{
    int b = blockIdx.x;
    const float* mb = m + (size_t)b * C_;
    int tid = threadIdx.x;
    float vals[8];
    float mx = -3.0e38f;
    #pragma unroll
    for (int i = 0; i < 8; ++i) {
        vals[i] = mb[tid + i*256];
        mx = fmaxf(mx, vals[i]);
    }
    #pragma unroll
    for (int o = 1; o < 64; o <<= 1) mx = fmaxf(mx, __shfl_xor(mx, o, 64));
    __shared__ float red[4], red2[4];
    int wv = tid >> 6, ln = tid & 63;
    if (ln == 0) red[wv] = mx;
    __syncthreads();
    mx = fmaxf(fmaxf(red[0], red[1]), fmaxf(red[2], red[3]));
    float s = 0.f;
    #pragma unroll
    for (int i = 0; i < 8; ++i) s += __expf(vals[i] - mx);
    #pragma unroll
    for (int o = 1; o < 64; o <<= 1) s += __shfl_xor(s, o, 64);
    if (ln == 0) red2[wv] = s;
    __syncthreads();
    if (tid == 0) {
        bstats[b*2]   = mx;
        bstats[b*2+1] = red2[0] + red2[1] + red2[2] + red2[3];
    }
}

// ---------------- q2c partials (deterministic, no atomics) ----------------
__global__ __launch_bounds__(256)
void cqa_q2c_part(const float* __restrict__ ctx, const float* __restrict__ m,
                  const float* __restrict__ bstats, float* __restrict__ part)
{
    int b = blockIdx.y, ch = blockIdx.x;
    int tid = threadIdx.x;
    int d = tid & 127, half = tid >> 7;
    float bmax = bstats[b*2];
    float inv  = 1.0f / bstats[b*2+1];
    const float* mb = m + (size_t)b*C_ + ch*256;
    const float* cb = ctx + ((size_t)b*C_ + ch*256) * D_;
    float acc = 0.f;
    for (int i = half; i < 256; i += 2) {
        float wgt = __expf(mb[i] - bmax);
        acc += wgt * cb[(size_t)i * D_ + d];
    }
    __shared__ float sh[128];
    if (half) sh[d] = acc;
    __syncthreads();
    if (!half) part[((size_t)b*8 + ch) * D_ + d] = (acc + sh[d]) * inv;
}

__global__ __launch_bounds__(256)
void cqa_q2c_sum(const float* __restrict__ part, float* __restrict__ q2c)
{
    int i = blockIdx.x * 256 + threadIdx.x;
    if (i >= B_ * D_) return;
    int b = i >> 7, d = i & 127;
    float s = 0.f;
    #pragma unroll
    for (int ch = 0; ch < 8; ++ch) s += part[((size_t)b*8 + ch)*D_ + d];
    q2c[i] = s;
}

// ---------------- out[:,:,384:512) = ctx * q2c (broadcast) ----------------
__global__ __launch_bounds__(256)
void cqa_out4(const float* __restrict__ ctx, const float* __restrict__ q2c,
              float* __restrict__ out)
{
    size_t i = (size_t)blockIdx.x * 256 + threadIdx.x;
    const size_t n4 = (size_t)B_*C_*D_/4;
    if (i >= n4) return;
    size_t bc = i >> 5;
    int d4 = (int)(i & 31);
    int b  = (int)(bc >> 11);
    float4 c4 = reinterpret_cast<const float4*>(ctx)[i];
    float4 g4 = reinterpret_cast<const float4*>(q2c)[b*32 + d4];
    float4 o;
    o.x = c4.x*g4.x; o.y = c4.y*g4.y; o.z = c4.z*g4.z; o.w = c4.w*g4.w;
    reinterpret_cast<float4*>(out)[bc*128 + 96 + d4] = o;
}

extern "C" void kernel_launch(void* const* d_in, const int* in_sizes, int n_in,
                              void* d_out, int out_size, void* d_ws, size_t ws_size,
                              hipStream_t stream)
{
    const float* ctx   = (const float*)d_in[0];
    const float* qry   = (const float*)d_in[1];
    const float* w     = (const float*)d_in[2];
    const int*   qmask = (const int*)d_in[3];
    float* out = (float*)d_out;
    float* ws  = (float*)d_ws;

    float* m_ws    = ws;                        // 65536 f32
    float* bstats  = ws + 65536;                // 64 (pad 128)
    float* part    = ws + 65664;                // 32768
    float* q2c     = ws + 98432;                // 4096
    float* qw2e_g  = ws + 102528;               // 4096
    unsigned short* bf = (unsigned short*)(ws + 106624);
    unsigned short* qw3Hi = bf;                 // 524288 each
    unsigned short* qw3Lo = bf + 524288;
    unsigned short* qTHi  = bf + 2*524288;
    unsigned short* qTLo  = bf + 3*524288;

    cqa_prep<<<dim3(8, B_), 256, 0, stream>>>(qry, w, qmask, qw2e_g,
                                              qw3Hi, qw3Lo, qTHi, qTLo);
    cqa_main<<<dim3(C_/CT, B_), 256, 0, stream>>>(ctx, w, qw2e_g,
                                                  qw3Hi, qw3Lo, qTHi, qTLo,
                                                  out, m_ws);
    cqa_bstats<<<B_, 256, 0, stream>>>(m_ws, bstats);
    cqa_q2c_part<<<dim3(8, B_), 256, 0, stream>>>(ctx, m_ws, bstats, part);
    cqa_q2c_sum<<<(B_*D_ + 255)/256, 256, 0, stream>>>(part, q2c);
    cqa_out4<<<(int)(((size_t)B_*C_*D_/4 + 255)/256), 256, 0, stream>>>(ctx, q2c, out);
}

// Round 9
// 57.989 us; speedup vs baseline: 2.4117x; 1.7400x over previous
//
#include <hip/hip_runtime.h>
#include <cstdint>

#define B_ 32
#define C_ 2048
#define Q_ 128
#define D_ 128
#define CT 64
#define OFF_ 8.0f
#define NEG_INF_F (-1.0e9f)

typedef __attribute__((ext_vector_type(8))) short bf16x8;
typedef __attribute__((ext_vector_type(4))) float f32x4;

__device__ inline short bf16_rne(float v) {
    unsigned u = __float_as_uint(v);
    return (short)((u + 0x7FFFu + ((u >> 16) & 1u)) >> 16);
}
__device__ inline void split_f32(float v, short& h, short& l) {
    unsigned u  = __float_as_uint(v);
    unsigned hb = u & 0xffff0000u;          // truncated bf16 (hi)
    float lo = v - __uint_as_float(hb);     // exact residual
    h = (short)(hb >> 16);
    l = (short)(__float_as_uint(lo) >> 16);
}

// ---------- prep: qw2e (q.w2 + mask), rne-bf16 of (qry*w3) and qry^T ----------
__global__ __launch_bounds__(256)
void cqa_prep(const float* __restrict__ qry, const float* __restrict__ w,
              const int* __restrict__ qmask, float* __restrict__ qw2e_g,
              unsigned short* __restrict__ qw3Hi, unsigned short* __restrict__ qTHi)
{
    const int b = blockIdx.y, ch = blockIdx.x;   // ch: 16-row chunk of q
    const int t = threadIdx.x;
    const float* qb = qry + (size_t)b * Q_ * D_;

    if (t < 32) {
        int rl = t >> 1, part = t & 1;
        int q = ch * 16 + rl;
        const float* p  = qb + q * D_ + part * 64;
        const float* wp = w + D_ + part * 64;
        float s = 0.f;
        #pragma unroll
        for (int j = 0; j < 64; j += 4) {
            float4 a4 = *(const float4*)(p + j);
            float4 w4 = *(const float4*)(wp + j);
            s += a4.x*w4.x + a4.y*w4.y + a4.z*w4.z + a4.w*w4.w;
        }
        s += __shfl_xor(s, 1, 2);
        if (!part) {
            float madd = (1.0f - (float)qmask[b * Q_ + q]) * NEG_INF_F;
            qw2e_g[b * Q_ + q] = s + madd;
        }
    }
    #pragma unroll
    for (int i = 0; i < 8; ++i) {
        int idx = t + i * 256;            // 16 rows x 128 d
        int ql = idx >> 7, d = idx & 127;
        int q = ch * 16 + ql;
        float v = qb[q * D_ + d];
        qw3Hi[((size_t)b * Q_ + q) * D_ + d] = (unsigned short)bf16_rne(v * w[2 * D_ + d]);
        qTHi[((size_t)b * D_ + d) * Q_ + q]  = (unsigned short)bf16_rne(v);
    }
}

// stage cols [col0,col0+32) of a [128][128]-short row-major matrix into an
// 8KB LDS buffer [128][32] via async DMA (linear LDS dest = base + lane*16B).
__device__ __forceinline__ void stage_b(const unsigned short* __restrict__ gH,
                                        int col0, short* sb, int wv, int lane)
{
    #pragma unroll
    for (int j = 0; j < 2; ++j) {
        int seg = wv * 2 + j;                 // 1KB segment 0..7
        int li  = seg * 64 + lane;            // 16B-unit linear index 0..511
        int row = li >> 2;
        int col = (li & 3) * 8;
        __builtin_amdgcn_global_load_lds(
            (const __attribute__((address_space(1))) void*)(gH + (size_t)row * 128 + col0 + col),
            (__attribute__((address_space(3))) void*)(sb + seg * 512), 16, 0, 0);
    }
}

// ---------- main: MFMA GEMMs + softmax + fused q2c partials + out[0:3D) ----------
__global__ __launch_bounds__(256, 4)
void cqa_main(const float* __restrict__ ctx, const float* __restrict__ w,
              const float* __restrict__ qw2e_g,
              const unsigned short* __restrict__ qw3Hi, const unsigned short* __restrict__ qTHi,
              float* __restrict__ out, float* __restrict__ part, float* __restrict__ denp_g)
{
    __shared__ __align__(16) char smem[35840];
    short* SB   = (short*)smem;                 // [0,16384): 2 x [128][32] dbuf
    short* PHi  = (short*)(smem + 16384);       // [64][136] bf16 (ends 33792)
    float* Tr   = (float*)smem;                 // [64][132] f32 overlay (33792 B)
    float* red  = (float*)smem;                 // [8][128] f32 overlay (post-Tr)
    float* mlds = (float*)(smem + 33792);       // 64 f32
    float* dred = (float*)(smem + 34048);       // 8 f32
    float* cw1  = (float*)(smem + 34304);       // 64 f32
    float* qw2e = (float*)(smem + 34560);       // 128 f32

    const int b   = blockIdx.y;
    const int c0  = blockIdx.x * CT;
    const int tid = threadIdx.x;
    const int lane = tid & 63;
    const int wv   = tid >> 6;
    const int w16  = wv * 16;
    const int lm   = lane & 15;
    const int lg   = lane >> 4;    // 0..3
    const int lk   = lg * 8;       // k-slot start within 32-chunk

    const float* ctxb = ctx + ((size_t)b * C_ + c0) * D_;
    const unsigned short* qw3Hb = qw3Hi + (size_t)b * Q_ * D_;
    const unsigned short* qTHb  = qTHi + (size_t)b * Q_ * D_;

    // kick off DMA of GEMM1 chunk 0 immediately
    stage_b(qw3Hb, 0, SB, wv, lane);

    // cw1[c] = ctx_row . w1 (4 threads/row, coalesced float4)
    {
        int row = tid >> 2, part4 = tid & 3;
        const float* p  = ctxb + row * D_ + part4 * 32;
        const float* wp = w + part4 * 32;
        float s = 0.f;
        #pragma unroll
        for (int j = 0; j < 32; j += 4) {
            float4 c4 = *(const float4*)(p + j);
            float4 w4 = *(const float4*)(wp + j);
            s += c4.x*w4.x + c4.y*w4.y + c4.z*w4.z + c4.w*w4.w;
        }
        s += __shfl_xor(s, 1, 4);
        s += __shfl_xor(s, 2, 4);
        if (!part4) cw1[row] = s;
    }
    if (tid < Q_) qw2e[tid] = qw2e_g[b * Q_ + tid];

    // preload ALL A-fragments (ctx rows, exact hi/lo split); overlaps DMA
    const float* arow = ctxb + (size_t)(w16 + lm) * D_;
    bf16x8 aHr[4], aLr[4];
    #pragma unroll
    for (int t = 0; t < 4; ++t) {
        float4 v0 = *(const float4*)(arow + t * 32 + lk);
        float4 v1 = *(const float4*)(arow + t * 32 + lk + 4);
        float vv[8] = {v0.x, v0.y, v0.z, v0.w, v1.x, v1.y, v1.z, v1.w};
        #pragma unroll
        for (int i = 0; i < 8; ++i) {
            short hh, ll; split_f32(vv[i], hh, ll);
            aHr[t][i] = hh; aLr[t][i] = ll;
        }
    }
    __syncthreads();   // stage(G1,0) drained; cw1/qw2e visible

    float qe[8];
    #pragma unroll
    for (int f = 0; f < 8; ++f) qe[f] = qw2e[f * 16 + lm];
    float cwr[4];
    #pragma unroll
    for (int r = 0; r < 4; ++r) cwr[r] = cw1[w16 + lg * 4 + r];

    const f32x4 vzero = {0.f, 0.f, 0.f, 0.f};
    f32x4 acc[8];
    #pragma unroll
    for (int f = 0; f < 8; ++f) acc[f] = vzero;

    // ---- GEMM1: S[c][q]; B(bf16 rne) from dbuf LDS, A(hi+lo) from regs
    #pragma unroll
    for (int t = 0; t < 4; ++t) {
        if (t < 3) stage_b(qw3Hb, (t + 1) * 32, SB + ((t + 1) & 1) * 4096, wv, lane);
        else       stage_b(qTHb,  0,            SB,                        wv, lane);
        const short* sb = SB + (t & 1) * 4096;
        bf16x8 aH = aHr[t], aL = aLr[t];
        #pragma unroll
        for (int f = 0; f < 8; ++f) {
            bf16x8 bH = *(const bf16x8*)(sb + (f * 16 + lm) * 32 + lk);
            acc[f] = __builtin_amdgcn_mfma_f32_16x16x32_bf16(aH, bH, acc[f], 0, 0, 0);
            acc[f] = __builtin_amdgcn_mfma_f32_16x16x32_bf16(aL, bH, acc[f], 0, 0, 0);
        }
        __syncthreads();   // drains stage issued above; guards dbuf reuse
    }

    // ---- softmax over q; P -> LDS bf16 rne (wave-private rows); m -> mlds
    float inv[4];
    #pragma unroll
    for (int r = 0; r < 4; ++r) {
        float sv[8];
        float mx = -3.0e38f;
        #pragma unroll
        for (int f = 0; f < 8; ++f) {
            sv[f] = acc[f][r] + qe[f];
            mx = fmaxf(mx, sv[f]);
        }
        mx = fmaxf(mx, __shfl_xor(mx, 1, 16));
        mx = fmaxf(mx, __shfl_xor(mx, 2, 16));
        mx = fmaxf(mx, __shfl_xor(mx, 4, 16));
        mx = fmaxf(mx, __shfl_xor(mx, 8, 16));
        int lrow = w16 + lg * 4 + r;
        float s = 0.f;
        #pragma unroll
        for (int f = 0; f < 8; ++f) {
            float p = __expf(sv[f] - mx);
            s += p;
            PHi[lrow * 136 + f * 16 + lm] = bf16_rne(p);
        }
        s += __shfl_xor(s, 1, 16);
        s += __shfl_xor(s, 2, 16);
        s += __shfl_xor(s, 4, 16);
        s += __shfl_xor(s, 8, 16);
        inv[r] = 1.0f / s;
        if (lm == 0) mlds[lrow] = mx + cwr[r];
    }
    // No barrier: P rows are wave-private; mlds consumed after later barriers

    // ---- GEMM2: c2q[c][d] = sum_q P[c][q]*qry[q][d]; A=P(LDS), B=qT(staged)
    f32x4 acc2[8];
    #pragma unroll
    for (int f = 0; f < 8; ++f) acc2[f] = vzero;

    #pragma unroll
    for (int t = 0; t < 4; ++t) {
        if (t < 3) stage_b(qTHb, (t + 1) * 32, SB + ((t + 1) & 1) * 4096, wv, lane);
        const short* sb = SB + (t & 1) * 4096;
        bf16x8 aH = *(const bf16x8*)(PHi + (w16 + lm) * 136 + t * 32 + lk);
        #pragma unroll
        for (int f = 0; f < 8; ++f) {
            bf16x8 bH = *(const bf16x8*)(sb + (f * 16 + lm) * 32 + lk);
            acc2[f] = __builtin_amdgcn_mfma_f32_16x16x32_bf16(aH, bH, acc2[f], 0, 0, 0);
        }
        __syncthreads();
    }

    // ---- transpose c2q through LDS (overlays SB+PHi; all reads complete)
    #pragma unroll
    for (int r = 0; r < 4; ++r) {
        int lrow = w16 + lg * 4 + r;
        #pragma unroll
        for (int f = 0; f < 8; ++f)
            Tr[lrow * 132 + f * 16 + lm] = acc2[f][r] * inv[r];
    }
    __syncthreads();

    // ---- epilogue: coalesced stores of out[0:3D) + fused q2c partials
    const int rsel = tid >> 5;            // 0..7
    const int dd   = (tid & 31) * 4;      // 0..124
    float4 qacc = {0.f, 0.f, 0.f, 0.f};
    float denp = 0.f;
    #pragma unroll
    for (int pass = 0; pass < 8; ++pass) {
        int row = pass * 8 + rsel;
        float4 a  = *(const float4*)(Tr + row * 132 + dd);
        float4 cv = *(const float4*)(ctxb + (size_t)row * D_ + dd);
        float wgt = __expf(mlds[row] - OFF_);
        size_t obase = ((size_t)b * C_ + c0 + row) * (4 * D_);
        float4 p;
        p.x = cv.x*a.x; p.y = cv.y*a.y; p.z = cv.z*a.z; p.w = cv.w*a.w;
        *(float4*)(out + obase + dd)          = cv;
        *(float4*)(out + obase + D_ + dd)     = a;
        *(float4*)(out + obase + 2 * D_ + dd) = p;
        qacc.x += wgt * cv.x; qacc.y += wgt * cv.y;
        qacc.z += wgt * cv.z; qacc.w += wgt * cv.w;
        denp += wgt;
    }
    __syncthreads();                       // Tr reads done; red may overlay
    *(float4*)(red + rsel * 128 + dd) = qacc;
    if ((tid & 31) == 0) dred[rsel] = denp;
    __syncthreads();
    if (tid < 128) {
        float s = 0.f;
        #pragma unroll
        for (int rr = 0; rr < 8; ++rr) s += red[rr * 128 + tid];
        part[((size_t)b * 32 + blockIdx.x) * 128 + tid] = s;
    }
    if (tid == 0) {
        float s = 0.f;
        #pragma unroll
        for (int rr = 0; rr < 8; ++rr) s += dred[rr];
        denp_g[b * 32 + blockIdx.x] = s;
    }
}

// ---------------- q2c: per-batch reduce of 32 partials ----------------
__global__ __launch_bounds__(128)
void cqa_q2c(const float* __restrict__ part, const float* __restrict__ denp_g,
             float* __restrict__ q2c)
{
    int b = blockIdx.x, d = threadIdx.x;
    float den = 0.f;
    #pragma unroll
    for (int j = 0; j < 32; ++j) den += denp_g[b * 32 + j];
    float s = 0.f;
    #pragma unroll
    for (int j = 0; j < 32; ++j) s += part[((size_t)b * 32 + j) * 128 + d];
    q2c[b * 128 + d] = s / den;
}

// ---------------- out[:,:,384:512) = ctx * q2c (broadcast) ----------------
__global__ __launch_bounds__(256)
void cqa_out4(const float* __restrict__ ctx, const float* __restrict__ q2c,
              float* __restrict__ out)
{
    size_t i = (size_t)blockIdx.x * 256 + threadIdx.x;
    const size_t n4 = (size_t)B_*C_*D_/4;
    if (i >= n4) return;
    size_t bc = i >> 5;
    int d4 = (int)(i & 31);
    int b  = (int)(bc >> 11);
    float4 c4 = reinterpret_cast<const float4*>(ctx)[i];
    float4 g4 = reinterpret_cast<const float4*>(q2c)[b*32 + d4];
    float4 o;
    o.x = c4.x*g4.x; o.y = c4.y*g4.y; o.z = c4.z*g4.z; o.w = c4.w*g4.w;
    reinterpret_cast<float4*>(out)[bc*128 + 96 + d4] = o;
}

extern "C" void kernel_launch(void* const* d_in, const int* in_sizes, int n_in,
                              void* d_out, int out_size, void* d_ws, size_t ws_size,
                              hipStream_t stream)
{
    const float* ctx   = (const float*)d_in[0];
    const float* qry   = (const float*)d_in[1];
    const float* w     = (const float*)d_in[2];
    const int*   qmask = (const int*)d_in[3];
    float* out = (float*)d_out;
    float* ws  = (float*)d_ws;

    float* part    = ws;                        // B*32*128 = 131072 f32
    float* denp_g  = ws + 131072;               // 1024
    float* q2c     = ws + 132096;               // 4096
    float* qw2e_g  = ws + 136192;               // 4096
    unsigned short* bf = (unsigned short*)(ws + 140288);
    unsigned short* qw3Hi = bf;                 // 524288 shorts
    unsigned short* qTHi  = bf + 524288;        // 524288 shorts

    cqa_prep<<<dim3(8, B_), 256, 0, stream>>>(qry, w, qmask, qw2e_g, qw3Hi, qTHi);
    cqa_main<<<dim3(C_/CT, B_), 256, 0, stream>>>(ctx, w, qw2e_g, qw3Hi, qTHi,
                                                  out, part, denp_g);
    cqa_q2c<<<B_, 128, 0, stream>>>(part, denp_g, q2c);
    cqa_out4<<<(int)(((size_t)B_*C_*D_/4 + 255)/256), 256, 0, stream>>>(ctx, q2c, out);
}

// Round 11
// 57.892 us; speedup vs baseline: 2.4158x; 1.0017x over previous
//
#include <hip/hip_runtime.h>
#include <hip/hip_cooperative_groups.h>
#include <cstdint>

namespace cg = cooperative_groups;

#define B_ 32
#define C_ 2048
#define Q_ 128
#define D_ 128
#define CT 64
#define OFF_ 8.0f
#define NEG_INF_F (-1.0e9f)

typedef __attribute__((ext_vector_type(8))) short bf16x8;
typedef __attribute__((ext_vector_type(4))) float f32x4;

__device__ inline short bf16_rne(float v) {
    unsigned u = __float_as_uint(v);
    return (short)((u + 0x7FFFu + ((u >> 16) & 1u)) >> 16);
}
__device__ inline void split_f32(float v, short& h, short& l) {
    unsigned u  = __float_as_uint(v);
    unsigned hb = u & 0xffff0000u;          // truncated bf16 (hi)
    float lo = v - __uint_as_float(hb);     // exact residual
    h = (short)(hb >> 16);
    l = (short)(__float_as_uint(lo) >> 16);
}

// ---------- prep: qw2e (q.w2 + mask), rne-bf16 of (qry*w3) and qry^T ----------
__global__ __launch_bounds__(256)
void cqa_prep(const float* __restrict__ qry, const float* __restrict__ w,
              const int* __restrict__ qmask, float* __restrict__ qw2e_g,
              unsigned short* __restrict__ qw3Hi, unsigned short* __restrict__ qTHi)
{
    const int b = blockIdx.y, ch = blockIdx.x;   // ch: 16-row chunk of q
    const int t = threadIdx.x;
    const float* qb = qry + (size_t)b * Q_ * D_;

    if (t < 32) {
        int rl = t >> 1, part = t & 1;
        int q = ch * 16 + rl;
        const float* p  = qb + q * D_ + part * 64;
        const float* wp = w + D_ + part * 64;
        float s = 0.f;
        #pragma unroll
        for (int j = 0; j < 64; j += 4) {
            float4 a4 = *(const float4*)(p + j);
            float4 w4 = *(const float4*)(wp + j);
            s += a4.x*w4.x + a4.y*w4.y + a4.z*w4.z + a4.w*w4.w;
        }
        s += __shfl_xor(s, 1, 2);
        if (!part) {
            float madd = (1.0f - (float)qmask[b * Q_ + q]) * NEG_INF_F;
            qw2e_g[b * Q_ + q] = s + madd;
        }
    }
    #pragma unroll
    for (int i = 0; i < 8; ++i) {
        int idx = t + i * 256;            // 16 rows x 128 d
        int ql = idx >> 7, d = idx & 127;
        int q = ch * 16 + ql;
        float v = qb[q * D_ + d];
        qw3Hi[((size_t)b * Q_ + q) * D_ + d] = (unsigned short)bf16_rne(v * w[2 * D_ + d]);
        qTHi[((size_t)b * D_ + d) * Q_ + q]  = (unsigned short)bf16_rne(v);
    }
}

// stage cols [col0,col0+32) of a [128][128]-short row-major matrix into an
// 8KB LDS buffer [128][32] via async DMA (linear LDS dest = base + lane*16B).
__device__ __forceinline__ void stage_b(const unsigned short* __restrict__ gH,
                                        int col0, short* sb, int wv, int lane)
{
    #pragma unroll
    for (int j = 0; j < 2; ++j) {
        int seg = wv * 2 + j;                 // 1KB segment 0..7
        int li  = seg * 64 + lane;            // 16B-unit linear index 0..511
        int row = li >> 2;
        int col = (li & 3) * 8;
        __builtin_amdgcn_global_load_lds(
            (const __attribute__((address_space(1))) void*)(gH + (size_t)row * 128 + col0 + col),
            (__attribute__((address_space(3))) void*)(sb + seg * 512), 16, 0, 0);
    }
}

// ---------- main: GEMMs + softmax + q2c partials + out slices ----------
// COOP=1: cooperative grid-sync, also writes slice 3 (needs agent-scope
//         atomics for the cross-XCD partial exchange — L2s not coherent).
// COOP=0: stops after partials; q2c/out4 kernels finish the job.
template<int COOP>
__global__ __launch_bounds__(256, 4)
void cqa_main(const float* __restrict__ ctx, const float* __restrict__ w,
              const float* __restrict__ qw2e_g,
              const unsigned short* __restrict__ qw3Hi, const unsigned short* __restrict__ qTHi,
              float* __restrict__ out, float* __restrict__ part, float* __restrict__ denp_g)
{
    __shared__ __align__(16) char smem[35840];
    short* SB   = (short*)smem;                 // [0,16384): 2 x [128][32] dbuf
    short* PHi  = (short*)(smem + 16384);       // [64][136] bf16 (ends 33792)
    float* Tr   = (float*)smem;                 // [64][132] f32 overlay (33792 B)
    float* red  = (float*)smem;                 // [8][128] f32 overlay (post-Tr)
    float* mlds = (float*)(smem + 33792);       // 64 f32
    float* dred = (float*)(smem + 34048);       // 8 f32
    float* cw1  = (float*)(smem + 34304);       // 64 f32
    float* qw2e = (float*)(smem + 34560);       // 128 f32

    const int b   = blockIdx.y;
    const int c0  = blockIdx.x * CT;
    const int tid = threadIdx.x;
    const int lane = tid & 63;
    const int wv   = tid >> 6;
    const int w16  = wv * 16;
    const int lm   = lane & 15;
    const int lg   = lane >> 4;    // 0..3
    const int lk   = lg * 8;       // k-slot start within 32-chunk

    const float* ctxb = ctx + ((size_t)b * C_ + c0) * D_;
    const unsigned short* qw3Hb = qw3Hi + (size_t)b * Q_ * D_;
    const unsigned short* qTHb  = qTHi + (size_t)b * Q_ * D_;

    // kick off DMA of GEMM1 chunk 0 immediately
    stage_b(qw3Hb, 0, SB, wv, lane);

    // cw1[c] = ctx_row . w1 (4 threads/row, coalesced float4)
    {
        int row = tid >> 2, part4 = tid & 3;
        const float* p  = ctxb + row * D_ + part4 * 32;
        const float* wp = w + part4 * 32;
        float s = 0.f;
        #pragma unroll
        for (int j = 0; j < 32; j += 4) {
            float4 c4 = *(const float4*)(p + j);
            float4 w4 = *(const float4*)(wp + j);
            s += c4.x*w4.x + c4.y*w4.y + c4.z*w4.z + c4.w*w4.w;
        }
        s += __shfl_xor(s, 1, 4);
        s += __shfl_xor(s, 2, 4);
        if (!part4) cw1[row] = s;
    }
    if (tid < Q_) qw2e[tid] = qw2e_g[b * Q_ + tid];

    // preload ALL A-fragments (ctx rows, exact hi/lo split); overlaps DMA
    const float* arow = ctxb + (size_t)(w16 + lm) * D_;
    bf16x8 aHr[4], aLr[4];
    #pragma unroll
    for (int t = 0; t < 4; ++t) {
        float4 v0 = *(const float4*)(arow + t * 32 + lk);
        float4 v1 = *(const float4*)(arow + t * 32 + lk + 4);
        float vv[8] = {v0.x, v0.y, v0.z, v0.w, v1.x, v1.y, v1.z, v1.w};
        #pragma unroll
        for (int i = 0; i < 8; ++i) {
            short hh, ll; split_f32(vv[i], hh, ll);
            aHr[t][i] = hh; aLr[t][i] = ll;
        }
    }
    __syncthreads();   // stage(G1,0) drained; cw1/qw2e visible

    float qe[8];
    #pragma unroll
    for (int f = 0; f < 8; ++f) qe[f] = qw2e[f * 16 + lm];
    float cwr[4];
    #pragma unroll
    for (int r = 0; r < 4; ++r) cwr[r] = cw1[w16 + lg * 4 + r];

    const f32x4 vzero = {0.f, 0.f, 0.f, 0.f};
    f32x4 acc[8];
    #pragma unroll
    for (int f = 0; f < 8; ++f) acc[f] = vzero;

    // ---- GEMM1: S[c][q]; B(bf16 rne) from dbuf LDS, A(hi+lo) from regs
    #pragma unroll
    for (int t = 0; t < 4; ++t) {
        if (t < 3) stage_b(qw3Hb, (t + 1) * 32, SB + ((t + 1) & 1) * 4096, wv, lane);
        else       stage_b(qTHb,  0,            SB,                        wv, lane);
        const short* sb = SB + (t & 1) * 4096;
        bf16x8 aH = aHr[t], aL = aLr[t];
        #pragma unroll
        for (int f = 0; f < 8; ++f) {
            bf16x8 bH = *(const bf16x8*)(sb + (f * 16 + lm) * 32 + lk);
            acc[f] = __builtin_amdgcn_mfma_f32_16x16x32_bf16(aH, bH, acc[f], 0, 0, 0);
            acc[f] = __builtin_amdgcn_mfma_f32_16x16x32_bf16(aL, bH, acc[f], 0, 0, 0);
        }
        __syncthreads();   // drains stage issued above; guards dbuf reuse
    }

    // ---- softmax over q; P -> LDS bf16 rne (wave-private rows); m -> mlds
    float inv[4];
    #pragma unroll
    for (int r = 0; r < 4; ++r) {
        float sv[8];
        float mx = -3.0e38f;
        #pragma unroll
        for (int f = 0; f < 8; ++f) {
            sv[f] = acc[f][r] + qe[f];
            mx = fmaxf(mx, sv[f]);
        }
        mx = fmaxf(mx, __shfl_xor(mx, 1, 16));
        mx = fmaxf(mx, __shfl_xor(mx, 2, 16));
        mx = fmaxf(mx, __shfl_xor(mx, 4, 16));
        mx = fmaxf(mx, __shfl_xor(mx, 8, 16));
        int lrow = w16 + lg * 4 + r;
        float s = 0.f;
        #pragma unroll
        for (int f = 0; f < 8; ++f) {
            float p = __expf(sv[f] - mx);
            s += p;
            PHi[lrow * 136 + f * 16 + lm] = bf16_rne(p);
        }
        s += __shfl_xor(s, 1, 16);
        s += __shfl_xor(s, 2, 16);
        s += __shfl_xor(s, 4, 16);
        s += __shfl_xor(s, 8, 16);
        inv[r] = 1.0f / s;
        if (lm == 0) mlds[lrow] = mx + cwr[r];
    }
    // No barrier: P rows are wave-private; mlds consumed after later barriers

    // ---- GEMM2: c2q[c][d] = sum_q P[c][q]*qry[q][d]; A=P(LDS), B=qT(staged)
    f32x4 acc2[8];
    #pragma unroll
    for (int f = 0; f < 8; ++f) acc2[f] = vzero;

    #pragma unroll
    for (int t = 0; t < 4; ++t) {
        if (t < 3) stage_b(qTHb, (t + 1) * 32, SB + ((t + 1) & 1) * 4096, wv, lane);
        const short* sb = SB + (t & 1) * 4096;
        bf16x8 aH = *(const bf16x8*)(PHi + (w16 + lm) * 136 + t * 32 + lk);
        #pragma unroll
        for (int f = 0; f < 8; ++f) {
            bf16x8 bH = *(const bf16x8*)(sb + (f * 16 + lm) * 32 + lk);
            acc2[f] = __builtin_amdgcn_mfma_f32_16x16x32_bf16(aH, bH, acc2[f], 0, 0, 0);
        }
        __syncthreads();
    }

    // ---- transpose c2q through LDS (overlays SB+PHi; all reads complete)
    #pragma unroll
    for (int r = 0; r < 4; ++r) {
        int lrow = w16 + lg * 4 + r;
        #pragma unroll
        for (int f = 0; f < 8; ++f)
            Tr[lrow * 132 + f * 16 + lm] = acc2[f][r] * inv[r];
    }
    __syncthreads();

    // ---- epilogue: coalesced stores of out[0:3D) + fused q2c partials;
    //      ctx fragments stashed in registers for the post-sync slice-3 write
    const int rsel = tid >> 5;            // 0..7
    const int dd   = (tid & 31) * 4;      // 0..124
    float4 ctxs[8];
    float4 qacc = {0.f, 0.f, 0.f, 0.f};
    float denp = 0.f;
    #pragma unroll
    for (int pass = 0; pass < 8; ++pass) {
        int row = pass * 8 + rsel;
        float4 a  = *(const float4*)(Tr + row * 132 + dd);
        float4 cv = *(const float4*)(ctxb + (size_t)row * D_ + dd);
        ctxs[pass] = cv;
        float wgt = __expf(mlds[row] - OFF_);
        size_t obase = ((size_t)b * C_ + c0 + row) * (4 * D_);
        float4 p;
        p.x = cv.x*a.x; p.y = cv.y*a.y; p.z = cv.z*a.z; p.w = cv.w*a.w;
        *(float4*)(out + obase + dd)          = cv;
        *(float4*)(out + obase + D_ + dd)     = a;
        *(float4*)(out + obase + 2 * D_ + dd) = p;
        qacc.x += wgt * cv.x; qacc.y += wgt * cv.y;
        qacc.z += wgt * cv.z; qacc.w += wgt * cv.w;
        denp += wgt;
    }
    __syncthreads();                       // Tr reads done; red may overlay
    *(float4*)(red + rsel * 128 + dd) = qacc;
    if ((tid & 31) == 0) dred[rsel] = denp;
    __syncthreads();
    // partial exchange: agent-scope atomics (cross-XCD L2s NOT coherent)
    if (tid < 128) {
        float s = 0.f;
        #pragma unroll
        for (int rr = 0; rr < 8; ++rr) s += red[rr * 128 + tid];
        __hip_atomic_store(&part[((size_t)b * 32 + blockIdx.x) * 128 + tid], s,
                           __ATOMIC_RELAXED, __HIP_MEMORY_SCOPE_AGENT);
    }
    if (tid == 0) {
        float s = 0.f;
        #pragma unroll
        for (int rr = 0; rr < 8; ++rr) s += dred[rr];
        __hip_atomic_store(&denp_g[b * 32 + blockIdx.x], s,
                           __ATOMIC_RELAXED, __HIP_MEMORY_SCOPE_AGENT);
    }

    if constexpr (COOP) {
        __threadfence();
        cg::this_grid().sync();

        // block-local coherent reduce of this batch's 32 partials -> LDS
        float* q2c_lds = red;              // 128 f32 (overlay, post-sync safe)
        float* dlds    = red + 128;        // 32 f32
        if (tid < 128) {
            float s = 0.f;
            #pragma unroll 8
            for (int j = 0; j < 32; ++j)
                s += __hip_atomic_load(&part[((size_t)b * 32 + j) * 128 + tid],
                                       __ATOMIC_RELAXED, __HIP_MEMORY_SCOPE_AGENT);
            q2c_lds[tid] = s;
        } else if (tid < 160) {
            dlds[tid - 128] = __hip_atomic_load(&denp_g[b * 32 + (tid - 128)],
                                                __ATOMIC_RELAXED, __HIP_MEMORY_SCOPE_AGENT);
        }
        __syncthreads();
        float den = 0.f;
        #pragma unroll
        for (int j = 0; j < 32; ++j) den += dlds[j];
        float idn = 1.0f / den;
        float4 qv = *(const float4*)(q2c_lds + dd);
        qv.x *= idn; qv.y *= idn; qv.z *= idn; qv.w *= idn;
        #pragma unroll
        for (int pass = 0; pass < 8; ++pass) {
            int row = pass * 8 + rsel;
            float4 cv = ctxs[pass];
            size_t obase = ((size_t)b * C_ + c0 + row) * (4 * D_);
            float4 o;
            o.x = cv.x*qv.x; o.y = cv.y*qv.y; o.z = cv.z*qv.z; o.w = cv.w*qv.w;
            *(float4*)(out + obase + 3 * D_ + dd) = o;
        }
    }
}

// ---------------- fallback: q2c reduce + slice-3 broadcast kernels ----------------
__global__ __launch_bounds__(128)
void cqa_q2c(const float* __restrict__ part, const float* __restrict__ denp_g,
             float* __restrict__ q2c)
{
    int b = blockIdx.x, d = threadIdx.x;
    float den = 0.f;
    #pragma unroll
    for (int j = 0; j < 32; ++j) den += denp_g[b * 32 + j];
    float s = 0.f;
    #pragma unroll
    for (int j = 0; j < 32; ++j) s += part[((size_t)b * 32 + j) * 128 + d];
    q2c[b * 128 + d] = s / den;
}

__global__ __launch_bounds__(256)
void cqa_out4(const float* __restrict__ ctx, const float* __restrict__ q2c,
              float* __restrict__ out)
{
    size_t i = (size_t)blockIdx.x * 256 + threadIdx.x;
    const size_t n4 = (size_t)B_*C_*D_/4;
    if (i >= n4) return;
    size_t bc = i >> 5;
    int d4 = (int)(i & 31);
    int b  = (int)(bc >> 11);
    float4 c4 = reinterpret_cast<const float4*>(ctx)[i];
    float4 g4 = reinterpret_cast<const float4*>(q2c)[b*32 + d4];
    float4 o;
    o.x = c4.x*g4.x; o.y = c4.y*g4.y; o.z = c4.z*g4.z; o.w = c4.w*g4.w;
    reinterpret_cast<float4*>(out)[bc*128 + 96 + d4] = o;
}

extern "C" void kernel_launch(void* const* d_in, const int* in_sizes, int n_in,
                              void* d_out, int out_size, void* d_ws, size_t ws_size,
                              hipStream_t stream)
{
    const float* ctx   = (const float*)d_in[0];
    const float* qry   = (const float*)d_in[1];
    const float* w     = (const float*)d_in[2];
    const int*   qmask = (const int*)d_in[3];
    float* out = (float*)d_out;
    float* ws  = (float*)d_ws;

    float* part    = ws;                        // B*32*128 = 131072 f32
    float* denp_g  = ws + 131072;               // 1024
    float* q2c     = ws + 132096;               // 4096
    float* qw2e_g  = ws + 136192;               // 4096
    unsigned short* bf = (unsigned short*)(ws + 140288);
    unsigned short* qw3Hi = bf;                 // 524288 shorts
    unsigned short* qTHi  = bf + 524288;        // 524288 shorts

    cqa_prep<<<dim3(8, B_), 256, 0, stream>>>(qry, w, qmask, qw2e_g, qw3Hi, qTHi);

    // capacity check (host-side queries only; capture-safe, deterministic)
    int dev = 0, cus = 0, maxb = 0;
    hipGetDevice(&dev);
    hipDeviceGetAttribute(&cus, hipDeviceAttributeMultiprocessorCount, dev);
    hipOccupancyMaxActiveBlocksPerMultiprocessor(&maxb, (const void*)cqa_main<1>, 256, 0);

    bool coop_ok = (cus > 0) && ((long)maxb * cus >= (long)(C_/CT) * B_);
    if (coop_ok) {
        void* args[] = { (void*)&ctx, (void*)&w, (void*)&qw2e_g,
                         (void*)&qw3Hi, (void*)&qTHi,
                         (void*)&out, (void*)&part, (void*)&denp_g };
        hipError_t e = hipLaunchCooperativeKernel((const void*)cqa_main<1>,
                                                  dim3(C_/CT, B_), dim3(256),
                                                  args, 0, stream);
        if (e == hipSuccess) return;
    }
    // fallback: non-cooperative path
    cqa_main<0><<<dim3(C_/CT, B_), 256, 0, stream>>>(ctx, w, qw2e_g, qw3Hi, qTHi,
                                                     out, part, denp_g);
    cqa_q2c<<<B_, 128, 0, stream>>>(part, denp_g, q2c);
    cqa_out4<<<(int)(((size_t)B_*C_*D_/4 + 255)/256), 256, 0, stream>>>(ctx, q2c, out);
}

// Round 12
// 53.952 us; speedup vs baseline: 2.5922x; 1.0730x over previous
//
#include <hip/hip_runtime.h>
#include <cstdint>

#define B_ 32
#define C_ 2048
#define Q_ 128
#define D_ 128
#define CT 64
#define OFF_ 8.0f
#define NEG_INF_F (-1.0e9f)

typedef __attribute__((ext_vector_type(8))) short bf16x8;
typedef __attribute__((ext_vector_type(4))) float f32x4;

__device__ inline short bf16_rne(float v) {
    unsigned u = __float_as_uint(v);
    return (short)((u + 0x7FFFu + ((u >> 16) & 1u)) >> 16);
}
__device__ inline void split_f32(float v, short& h, short& l) {
    unsigned u  = __float_as_uint(v);
    unsigned hb = u & 0xffff0000u;          // truncated bf16 (hi)
    float lo = v - __uint_as_float(hb);     // exact residual (Sterbenz)
    h = (short)(hb >> 16);
    l = (short)(__float_as_uint(lo) >> 16);
}

// ---------- prep: qw2e (q.w2 + mask), rne-bf16 of (qry*w3) and qry^T ----------
__global__ __launch_bounds__(256)
void cqa_prep(const float* __restrict__ qry, const float* __restrict__ w,
              const int* __restrict__ qmask, float* __restrict__ qw2e_g,
              unsigned short* __restrict__ qw3Hi, unsigned short* __restrict__ qTHi)
{
    const int b = blockIdx.y, ch = blockIdx.x;   // ch: 16-row chunk of q
    const int t = threadIdx.x;
    const float* qb = qry + (size_t)b * Q_ * D_;

    if (t < 32) {
        int rl = t >> 1, part = t & 1;
        int q = ch * 16 + rl;
        const float* p  = qb + q * D_ + part * 64;
        const float* wp = w + D_ + part * 64;
        float s = 0.f;
        #pragma unroll
        for (int j = 0; j < 64; j += 4) {
            float4 a4 = *(const float4*)(p + j);
            float4 w4 = *(const float4*)(wp + j);
            s += a4.x*w4.x + a4.y*w4.y + a4.z*w4.z + a4.w*w4.w;
        }
        s += __shfl_xor(s, 1, 2);
        if (!part) {
            float madd = (1.0f - (float)qmask[b * Q_ + q]) * NEG_INF_F;
            qw2e_g[b * Q_ + q] = s + madd;
        }
    }
    #pragma unroll
    for (int i = 0; i < 8; ++i) {
        int idx = t + i * 256;            // 16 rows x 128 d
        int ql = idx >> 7, d = idx & 127;
        int q = ch * 16 + ql;
        float v = qb[q * D_ + d];
        qw3Hi[((size_t)b * Q_ + q) * D_ + d] = (unsigned short)bf16_rne(v * w[2 * D_ + d]);
        qTHi[((size_t)b * D_ + d) * Q_ + q]  = (unsigned short)bf16_rne(v);
    }
}

// stage cols [col0,col0+32) of a [128][128]-short row-major matrix into an
// 8KB LDS buffer [128][32] via async DMA (linear LDS dest = base + lane*16B).
__device__ __forceinline__ void stage_b(const unsigned short* __restrict__ gH,
                                        int col0, short* sb, int wv, int lane)
{
    #pragma unroll
    for (int j = 0; j < 2; ++j) {
        int seg = wv * 2 + j;                 // 1KB segment 0..7
        int li  = seg * 64 + lane;            // 16B-unit linear index 0..511
        int row = li >> 2;
        int col = (li & 3) * 8;
        __builtin_amdgcn_global_load_lds(
            (const __attribute__((address_space(1))) void*)(gH + (size_t)row * 128 + col0 + col),
            (__attribute__((address_space(3))) void*)(sb + seg * 512), 16, 0, 0);
    }
}

// ---------- main: MFMA GEMMs + softmax + fused q2c partials + out[0:3D) ----------
__global__ __launch_bounds__(256, 4)
void cqa_main(const float* __restrict__ ctx, const float* __restrict__ w,
              const float* __restrict__ qw2e_g,
              const unsigned short* __restrict__ qw3Hi, const unsigned short* __restrict__ qTHi,
              float* __restrict__ out, float* __restrict__ part, float* __restrict__ denp_g)
{
    __shared__ __align__(16) char smem[35840];
    short* SB   = (short*)smem;                 // [0,16384): 2 x [128][32] dbuf
    short* PHi  = (short*)(smem + 16384);       // [64][136] bf16 (ends 33792)
    float* Tr   = (float*)smem;                 // [64][132] f32 overlay (33792 B)
    float* red  = (float*)smem;                 // [8][128] f32 overlay (post-Tr)
    float* mlds = (float*)(smem + 33792);       // 64 f32
    float* dred = (float*)(smem + 34048);       // 8 f32
    float* cw1  = (float*)(smem + 34304);       // 64 f32
    float* qw2e = (float*)(smem + 34560);       // 128 f32

    const int b   = blockIdx.y;
    const int c0  = blockIdx.x * CT;
    const int tid = threadIdx.x;
    const int lane = tid & 63;
    const int wv   = tid >> 6;
    const int w16  = wv * 16;
    const int lm   = lane & 15;
    const int lg   = lane >> 4;    // 0..3
    const int lk   = lg * 8;       // k-slot start within 32-chunk

    const float* ctxb = ctx + ((size_t)b * C_ + c0) * D_;
    const unsigned short* qw3Hb = qw3Hi + (size_t)b * Q_ * D_;
    const unsigned short* qTHb  = qTHi + (size_t)b * Q_ * D_;

    // kick off DMA of GEMM1 chunk 0 immediately
    stage_b(qw3Hb, 0, SB, wv, lane);

    if (tid < Q_) qw2e[tid] = qw2e_g[b * Q_ + tid];

    // A-preload (ctx rows, exact hi/lo split) with FUSED cw1 = ctx_row . w1:
    // lane (lg,lm) holds 8 floats x 4 chunks of row w16+lm; dot each slice
    // with w1 and reduce across the 4 lg-lanes (shfl_xor 16/32).
    const float* arow = ctxb + (size_t)(w16 + lm) * D_;
    bf16x8 aHr[4], aLr[4];
    float cws = 0.f;
    #pragma unroll
    for (int t = 0; t < 4; ++t) {
        float4 v0 = *(const float4*)(arow + t * 32 + lk);
        float4 v1 = *(const float4*)(arow + t * 32 + lk + 4);
        float4 w0 = *(const float4*)(w + t * 32 + lk);
        float4 w1v = *(const float4*)(w + t * 32 + lk + 4);
        cws += v0.x*w0.x + v0.y*w0.y + v0.z*w0.z + v0.w*w0.w
             + v1.x*w1v.x + v1.y*w1v.y + v1.z*w1v.z + v1.w*w1v.w;
        float vv[8] = {v0.x, v0.y, v0.z, v0.w, v1.x, v1.y, v1.z, v1.w};
        #pragma unroll
        for (int i = 0; i < 8; ++i) {
            short hh, ll; split_f32(vv[i], hh, ll);
            aHr[t][i] = hh; aLr[t][i] = ll;
        }
    }
    cws += __shfl_xor(cws, 16, 64);
    cws += __shfl_xor(cws, 32, 64);
    if (lane < 16) cw1[w16 + lm] = cws;
    __syncthreads();   // stage(G1,0) drained; cw1/qw2e visible

    float qe[8];
    #pragma unroll
    for (int f = 0; f < 8; ++f) qe[f] = qw2e[f * 16 + lm];
    float cwr[4];
    #pragma unroll
    for (int r = 0; r < 4; ++r) cwr[r] = cw1[w16 + lg * 4 + r];

    const f32x4 vzero = {0.f, 0.f, 0.f, 0.f};
    f32x4 acc[8];
    #pragma unroll
    for (int f = 0; f < 8; ++f) acc[f] = vzero;

    // ---- GEMM1: S[c][q]; B(bf16 rne) from dbuf LDS, A(hi+lo) from regs
    #pragma unroll
    for (int t = 0; t < 4; ++t) {
        if (t < 3) stage_b(qw3Hb, (t + 1) * 32, SB + ((t + 1) & 1) * 4096, wv, lane);
        else       stage_b(qTHb,  0,            SB,                        wv, lane);
        const short* sb = SB + (t & 1) * 4096;
        bf16x8 aH = aHr[t], aL = aLr[t];
        #pragma unroll
        for (int f = 0; f < 8; ++f) {
            bf16x8 bH = *(const bf16x8*)(sb + (f * 16 + lm) * 32 + lk);
            acc[f] = __builtin_amdgcn_mfma_f32_16x16x32_bf16(aH, bH, acc[f], 0, 0, 0);
            acc[f] = __builtin_amdgcn_mfma_f32_16x16x32_bf16(aL, bH, acc[f], 0, 0, 0);
        }
        __syncthreads();   // drains stage issued above; guards dbuf reuse
    }

    // ---- softmax over q; P -> LDS bf16 rne (wave-private rows); m -> mlds
    float inv[4];
    #pragma unroll
    for (int r = 0; r < 4; ++r) {
        float sv[8];
        float mx = -3.0e38f;
        #pragma unroll
        for (int f = 0; f < 8; ++f) {
            sv[f] = acc[f][r] + qe[f];
            mx = fmaxf(mx, sv[f]);
        }
        mx = fmaxf(mx, __shfl_xor(mx, 1, 16));
        mx = fmaxf(mx, __shfl_xor(mx, 2, 16));
        mx = fmaxf(mx, __shfl_xor(mx, 4, 16));
        mx = fmaxf(mx, __shfl_xor(mx, 8, 16));
        int lrow = w16 + lg * 4 + r;
        float s = 0.f;
        #pragma unroll
        for (int f = 0; f < 8; ++f) {
            float p = __expf(sv[f] - mx);
            s += p;
            PHi[lrow * 136 + f * 16 + lm] = bf16_rne(p);
        }
        s += __shfl_xor(s, 1, 16);
        s += __shfl_xor(s, 2, 16);
        s += __shfl_xor(s, 4, 16);
        s += __shfl_xor(s, 8, 16);
        inv[r] = 1.0f / s;
        if (lm == 0) mlds[lrow] = mx + cwr[r];
    }
    // No barrier: P rows are wave-private; mlds consumed after later barriers

    // ---- GEMM2: c2q[c][d] = sum_q P[c][q]*qry[q][d]; A=P(LDS), B=qT(staged)
    f32x4 acc2[8];
    #pragma unroll
    for (int f = 0; f < 8; ++f) acc2[f] = vzero;

    #pragma unroll
    for (int t = 0; t < 4; ++t) {
        if (t < 3) stage_b(qTHb, (t + 1) * 32, SB + ((t + 1) & 1) * 4096, wv, lane);
        const short* sb = SB + (t & 1) * 4096;
        bf16x8 aH = *(const bf16x8*)(PHi + (w16 + lm) * 136 + t * 32 + lk);
        #pragma unroll
        for (int f = 0; f < 8; ++f) {
            bf16x8 bH = *(const bf16x8*)(sb + (f * 16 + lm) * 32 + lk);
            acc2[f] = __builtin_amdgcn_mfma_f32_16x16x32_bf16(aH, bH, acc2[f], 0, 0, 0);
        }
        __syncthreads();
    }

    // ---- transpose c2q through LDS (overlays SB+PHi; all reads complete)
    #pragma unroll
    for (int r = 0; r < 4; ++r) {
        int lrow = w16 + lg * 4 + r;
        #pragma unroll
        for (int f = 0; f < 8; ++f)
            Tr[lrow * 132 + f * 16 + lm] = acc2[f][r] * inv[r];
    }
    __syncthreads();

    // ---- epilogue: coalesced stores of out[0:3D) + fused q2c partials
    const int rsel = tid >> 5;            // 0..7
    const int dd   = (tid & 31) * 4;      // 0..124
    float4 qacc = {0.f, 0.f, 0.f, 0.f};
    float denp = 0.f;
    #pragma unroll
    for (int pass = 0; pass < 8; ++pass) {
        int row = pass * 8 + rsel;
        float4 a  = *(const float4*)(Tr + row * 132 + dd);
        float4 cv = *(const float4*)(ctxb + (size_t)row * D_ + dd);
        float wgt = __expf(mlds[row] - OFF_);
        size_t obase = ((size_t)b * C_ + c0 + row) * (4 * D_);
        float4 p;
        p.x = cv.x*a.x; p.y = cv.y*a.y; p.z = cv.z*a.z; p.w = cv.w*a.w;
        *(float4*)(out + obase + dd)          = cv;
        *(float4*)(out + obase + D_ + dd)     = a;
        *(float4*)(out + obase + 2 * D_ + dd) = p;
        qacc.x += wgt * cv.x; qacc.y += wgt * cv.y;
        qacc.z += wgt * cv.z; qacc.w += wgt * cv.w;
        denp += wgt;
    }
    __syncthreads();                       // Tr reads done; red may overlay
    *(float4*)(red + rsel * 128 + dd) = qacc;
    if ((tid & 31) == 0) dred[rsel] = denp;
    __syncthreads();
    if (tid < 128) {
        float s = 0.f;
        #pragma unroll
        for (int rr = 0; rr < 8; ++rr) s += red[rr * 128 + tid];
        part[((size_t)b * 32 + blockIdx.x) * 128 + tid] = s;
    }
    if (tid == 0) {
        float s = 0.f;
        #pragma unroll
        for (int rr = 0; rr < 8; ++rr) s += dred[rr];
        denp_g[b * 32 + blockIdx.x] = s;
    }
}

// ---------------- q2c: per-batch reduce of 32 partials ----------------
__global__ __launch_bounds__(128)
void cqa_q2c(const float* __restrict__ part, const float* __restrict__ denp_g,
             float* __restrict__ q2c)
{
    int b = blockIdx.x, d = threadIdx.x;
    float den = 0.f;
    #pragma unroll
    for (int j = 0; j < 32; ++j) den += denp_g[b * 32 + j];
    float s = 0.f;
    #pragma unroll
    for (int j = 0; j < 32; ++j) s += part[((size_t)b * 32 + j) * 128 + d];
    q2c[b * 128 + d] = s / den;
}

// ---------------- out[:,:,384:512) = ctx * q2c (broadcast) ----------------
__global__ __launch_bounds__(256)
void cqa_out4(const float* __restrict__ ctx, const float* __restrict__ q2c,
              float* __restrict__ out)
{
    size_t i = (size_t)blockIdx.x * 256 + threadIdx.x;
    const size_t n4 = (size_t)B_*C_*D_/4;
    if (i >= n4) return;
    size_t bc = i >> 5;
    int d4 = (int)(i & 31);
    int b  = (int)(bc >> 11);
    float4 c4 = reinterpret_cast<const float4*>(ctx)[i];
    float4 g4 = reinterpret_cast<const float4*>(q2c)[b*32 + d4];
    float4 o;
    o.x = c4.x*g4.x; o.y = c4.y*g4.y; o.z = c4.z*g4.z; o.w = c4.w*g4.w;
    reinterpret_cast<float4*>(out)[bc*128 + 96 + d4] = o;
}

extern "C" void kernel_launch(void* const* d_in, const int* in_sizes, int n_in,
                              void* d_out, int out_size, void* d_ws, size_t ws_size,
                              hipStream_t stream)
{
    const float* ctx   = (const float*)d_in[0];
    const float* qry   = (const float*)d_in[1];
    const float* w     = (const float*)d_in[2];
    const int*   qmask = (const int*)d_in[3];
    float* out = (float*)d_out;
    float* ws  = (float*)d_ws;

    float* part    = ws;                        // B*32*128 = 131072 f32
    float* denp_g  = ws + 131072;               // 1024
    float* q2c     = ws + 132096;               // 4096
    float* qw2e_g  = ws + 136192;               // 4096
    unsigned short* bf = (unsigned short*)(ws + 140288);
    unsigned short* qw3Hi = bf;                 // 524288 shorts
    unsigned short* qTHi  = bf + 524288;        // 524288 shorts

    cqa_prep<<<dim3(8, B_), 256, 0, stream>>>(qry, w, qmask, qw2e_g, qw3Hi, qTHi);
    cqa_main<<<dim3(C_/CT, B_), 256, 0, stream>>>(ctx, w, qw2e_g, qw3Hi, qTHi,
                                                  out, part, denp_g);
    cqa_q2c<<<B_, 128, 0, stream>>>(part, denp_g, q2c);
    cqa_out4<<<(int)(((size_t)B_*C_*D_/4 + 255)/256), 256, 0, stream>>>(ctx, q2c, out);
}